// Round 6
// baseline (124.926 us; speedup 1.0000x reference)
//
#include <hip/hip_runtime.h>
#include <math.h>

// GMMflow_fast: B=2048, M=1024, D=64.  Single-kernel MFMA formulation, R6.
//   Inline prep (per block, 64 m): a=1/Sigma, p'=-2*mut*a, q[m]; K,g stashed bf16.
//   GEMM1 (3-pass bf16 hi/lo, K=128): C1[b,m] = A1[b,:]·B1[m,:], A1=[x^2|x], B1=[a|p']
//   w = exp(clip(-0.5*(C1+q)))*Lam; norm via shfl-reduce of bf16-rounded w
//   GEMM2 (single bf16, K=64m, N=128): C3 = W·V, V=[K|g]
//   Partials per (split,b); last block per b-column (device atomic counter,
//   __threadfence release/acquire for cross-XCD visibility) reduces + writes u.

#define B_N 2048
#define M_N 1024
#define NSPLIT 16
#define BT 64
#define MS 64
#define PROW 132   // 64 S1 | 64 S2 | norm0 norm1 | pad

typedef short bf16x8 __attribute__((ext_vector_type(8)));
typedef float f32x4 __attribute__((ext_vector_type(4)));

static __device__ __forceinline__ unsigned short bf16rn(float f) {
    union { float f; unsigned u; } v; v.f = f;
    unsigned r = v.u + 0x7FFF + ((v.u >> 16) & 1);
    return (unsigned short)(r >> 16);
}
static __device__ __forceinline__ float bf2f(unsigned short h) {
    union { unsigned u; float f; } v; v.u = ((unsigned)h) << 16;
    return v.f;
}
static __device__ __forceinline__ void st4(unsigned short* p, unsigned short a,
                                           unsigned short b, unsigned short c, unsigned short d) {
    union { unsigned short u[4]; float2 f; } t;
    t.u[0] = a; t.u[1] = b; t.u[2] = c; t.u[3] = d;
    *(float2*)p = t.f;
}

// grid (32,16) = 512 blocks, 256 thr, ~70.3 KB LDS, 2 blocks/CU.
__global__ __launch_bounds__(256, 2)
void gmm_main_kernel(const float* __restrict__ X,
                     const float* __restrict__ Mu0, const float* __restrict__ Mu1,
                     const float* __restrict__ S0, const float* __restrict__ S1,
                     const float* __restrict__ Lam,
                     const float* __restrict__ T, const float* __restrict__ E,
                     float* __restrict__ part, int* __restrict__ cnt,
                     float* __restrict__ out) {
    __shared__ __align__(16) char smem_raw[70400];
    unsigned short* sm = (unsigned short*)smem_raw;
    unsigned short* sA1h = sm;                // 8704 us
    unsigned short* sA1l = sm + 8704;
    unsigned short* sB1h = sm + 17408;
    unsigned short* sB1l = sm + 26112;        // region end 34816 us (69632 B)
    unsigned short* sV   = sm;                // overlay on A: 128x72 = 9216 us
    unsigned short* sW   = sm + 17408;        // overlay on B: 64x72 = 4608 us
    float* sQ = (float*)(smem_raw + 69632);   // 64 f
    float* sL = (float*)(smem_raw + 69888);   // 64 f
    int*  sWin = (int*)(smem_raw + 70144);

    const int tid  = threadIdx.x;
    const int Boff = blockIdx.x * BT;
    const int Moff = blockIdx.y * MS;
    const int w    = tid >> 6;
    const int lane = tid & 63;
    const int c = lane & 15, q = lane >> 4;
    const int wb = w >> 1;     // b-half
    const int wm = w & 1;      // GEMM1 m-half / GEMM2 n-half
    const int d  = lane;       // prep: dim index
    const int mq = tid >> 6;   // prep: m-subgroup

    // ---- inline prep: component math for this block's 64 m ----
    ushort2 kg[16];   // stashed bf16 (K,g) per handled (m,d)
    {
        const float t = T[0], e = E[0];
        const float eps2 = e * e, eps4 = eps2 * eps2, omt = 1.f - t;
        #pragma unroll 4
        for (int it = 0; it < 16; it++) {
            int mloc = it * 4 + mq;
            int idx = (Moff + mloc) * 64 + d;
            float s0 = S0[idx], s1 = S1[idx];
            float mu0 = Mu0[idx], mu1 = Mu1[idx];
            float Ds = sqrtf(4.f * s0 * s1 + eps4);
            float Cs = 0.5f * (Ds - eps2);
            float sig = omt * omt * s0 + t * t * s1 + 2.f * t * omt * (Cs + 0.5f * eps2);
            float St = (t * s1 + omt * Cs) - (omt * s0 + t * Cs) - eps2 * t;
            float a = 1.f / sig;
            float K = St * a;
            float mut = omt * mu0 + t * mu1;
            float pp = -2.f * mut * a;
            float g = (mu1 - mu0) - K * mut;
            unsigned short ah = bf16rn(a);
            sB1h[mloc * 136 + d] = ah;
            sB1l[mloc * 136 + d] = bf16rn(a - bf2f(ah));
            unsigned short ph = bf16rn(pp);
            sB1h[mloc * 136 + 64 + d] = ph;
            sB1l[mloc * 136 + 64 + d] = bf16rn(pp - bf2f(ph));
            kg[it] = make_ushort2(bf16rn(K), bf16rn(g));
            float qd = mut * mut * a + __logf(sig);
            #pragma unroll
            for (int off = 32; off > 0; off >>= 1) qd += __shfl_xor(qd, off, 64);
            if (d == 0) sQ[mloc] = qd;
        }
        if (tid < 64) sL[tid] = Lam[Moff + tid];
    }
    // ---- stage A1 from X (hi/lo of x^2, x) ----
    {
        const float4* X4 = (const float4*)X;
        #pragma unroll
        for (int it = 0; it < 4; it++) {
            int i = it * 256 + tid;            // 64 b x 16 f4
            int b = i >> 4, dq4 = i & 15;
            float4 xv = X4[(size_t)(Boff + b) * 16 + dq4];
            float xs[4] = {xv.x, xv.y, xv.z, xv.w};
            unsigned short yh[4], yl[4], xh[4], xl[4];
            #pragma unroll
            for (int k = 0; k < 4; k++) {
                float y = xs[k] * xs[k];
                yh[k] = bf16rn(y);  yl[k] = bf16rn(y - bf2f(yh[k]));
                xh[k] = bf16rn(xs[k]);  xl[k] = bf16rn(xs[k] - bf2f(xh[k]));
            }
            int base = b * 136 + 4 * dq4;
            st4(sA1h + base, yh[0], yh[1], yh[2], yh[3]);
            st4(sA1l + base, yl[0], yl[1], yl[2], yl[3]);
            st4(sA1h + base + 64, xh[0], xh[1], xh[2], xh[3]);
            st4(sA1l + base + 64, xl[0], xl[1], xl[2], xl[3]);
        }
    }
    __syncthreads();

    // ---- GEMM1: wave quadrant 32b x 32m, K=128, 3 hi/lo passes ----
    f32x4 acc1[2][2];
    #pragma unroll
    for (int i = 0; i < 2; i++)
        #pragma unroll
        for (int j = 0; j < 2; j++) acc1[i][j] = (f32x4){0.f, 0.f, 0.f, 0.f};
    #pragma unroll
    for (int ks = 0; ks < 4; ks++) {
        bf16x8 Ah[2], Al[2], Bh[2], Bl[2];
        #pragma unroll
        for (int i = 0; i < 2; i++) {
            int row = wb * 32 + i * 16 + c;
            Ah[i] = *(const bf16x8*)(sA1h + row * 136 + ks * 32 + q * 8);
            Al[i] = *(const bf16x8*)(sA1l + row * 136 + ks * 32 + q * 8);
        }
        #pragma unroll
        for (int j = 0; j < 2; j++) {
            int row = wm * 32 + j * 16 + c;
            Bh[j] = *(const bf16x8*)(sB1h + row * 136 + ks * 32 + q * 8);
            Bl[j] = *(const bf16x8*)(sB1l + row * 136 + ks * 32 + q * 8);
        }
        #pragma unroll
        for (int i = 0; i < 2; i++)
            #pragma unroll
            for (int j = 0; j < 2; j++) {
                acc1[i][j] = __builtin_amdgcn_mfma_f32_16x16x32_bf16(Ah[i], Bh[j], acc1[i][j], 0, 0, 0);
                acc1[i][j] = __builtin_amdgcn_mfma_f32_16x16x32_bf16(Ah[i], Bl[j], acc1[i][j], 0, 0, 0);
                acc1[i][j] = __builtin_amdgcn_mfma_f32_16x16x32_bf16(Al[i], Bh[j], acc1[i][j], 0, 0, 0);
            }
    }
    __syncthreads();   // A/B regions dead -> overlays

    // ---- write V from stashed kg + compute W + consistent norm ----
    {
        #pragma unroll 4
        for (int it = 0; it < 16; it++) {
            int mloc = it * 4 + mq;
            sV[d * 72 + mloc]        = kg[it].x;   // K rows n=0..63
            sV[(64 + d) * 72 + mloc] = kg[it].y;   // g rows n=64..127
        }
        float nsum[2][4];
        #pragma unroll
        for (int i = 0; i < 2; i++)
            #pragma unroll
            for (int r = 0; r < 4; r++) nsum[i][r] = 0.f;
        #pragma unroll
        for (int i = 0; i < 2; i++)
            #pragma unroll
            for (int j = 0; j < 2; j++) {
                int m = wm * 32 + j * 16 + c;
                float qm = sQ[m], lm = sL[m];
                #pragma unroll
                for (int r = 0; r < 4; r++) {
                    int bl = wb * 32 + i * 16 + q * 4 + r;
                    float lw = -0.5f * (acc1[i][j][r] + qm);
                    lw = fminf(50.f, fmaxf(-50.f, lw));
                    float wf = __expf(lw) * lm;
                    unsigned short wh = bf16rn(wf);
                    sW[bl * 72 + m] = wh;
                    nsum[i][r] += bf2f(wh);
                }
            }
        #pragma unroll
        for (int mask = 1; mask <= 8; mask <<= 1)
            #pragma unroll
            for (int i = 0; i < 2; i++)
                #pragma unroll
                for (int r = 0; r < 4; r++)
                    nsum[i][r] += __shfl_xor(nsum[i][r], mask, 64);
        if (c == 0) {
            #pragma unroll
            for (int i = 0; i < 2; i++)
                #pragma unroll
                for (int r = 0; r < 4; r++) {
                    int b = Boff + wb * 32 + i * 16 + q * 4 + r;
                    part[((size_t)blockIdx.y * B_N + b) * PROW + 128 + wm] = nsum[i][r];
                }
        }
    }
    __syncthreads();

    // ---- GEMM2: wave 32b x 64n, K=64, single pass ----
    f32x4 acc2[2][4];
    #pragma unroll
    for (int i = 0; i < 2; i++)
        #pragma unroll
        for (int j = 0; j < 4; j++) acc2[i][j] = (f32x4){0.f, 0.f, 0.f, 0.f};
    #pragma unroll
    for (int ks = 0; ks < 2; ks++) {
        bf16x8 Wf[2], Vf[4];
        #pragma unroll
        for (int i = 0; i < 2; i++) {
            int row = wb * 32 + i * 16 + c;
            Wf[i] = *(const bf16x8*)(sW + row * 72 + ks * 32 + q * 8);
        }
        #pragma unroll
        for (int j = 0; j < 4; j++) {
            int row = wm * 64 + j * 16 + c;
            Vf[j] = *(const bf16x8*)(sV + row * 72 + ks * 32 + q * 8);
        }
        #pragma unroll
        for (int i = 0; i < 2; i++)
            #pragma unroll
            for (int j = 0; j < 4; j++)
                acc2[i][j] = __builtin_amdgcn_mfma_f32_16x16x32_bf16(Wf[i], Vf[j], acc2[i][j], 0, 0, 0);
    }

    // ---- partial S1|S2 writes ----
    #pragma unroll
    for (int i = 0; i < 2; i++)
        #pragma unroll
        for (int j = 0; j < 4; j++) {
            #pragma unroll
            for (int r = 0; r < 4; r++) {
                int b = Boff + wb * 32 + i * 16 + q * 4 + r;
                int n = wm * 64 + j * 16 + c;
                part[((size_t)blockIdx.y * B_N + b) * PROW + n] = acc2[i][j][r];
            }
        }

    // ---- completion protocol: last block per b-column reduces ----
    __syncthreads();   // drains vmcnt: all partial stores complete at L2
    if (tid == 0) {
        __threadfence();                       // device-scope release (L2 writeback)
        int old = atomicAdd(&cnt[blockIdx.x], 1);
        *sWin = (old == NSPLIT - 1);
    }
    __syncthreads();
    if (!*sWin) return;
    __threadfence();                           // acquire: invalidate stale lines

    {
        int b = Boff + (tid >> 2);
        int d0 = (tid & 3) * 16;
        float a1[16], a2[16], nn = 0.f;
        #pragma unroll
        for (int k = 0; k < 16; k++) { a1[k] = 0.f; a2[k] = 0.f; }
        for (int s = 0; s < NSPLIT; s++) {
            const float* row = part + ((size_t)s * B_N + b) * PROW;
            #pragma unroll
            for (int k = 0; k < 4; k++) {
                float4 v1 = *(const float4*)(row + d0 + 4 * k);
                float4 v2 = *(const float4*)(row + 64 + d0 + 4 * k);
                a1[4 * k] += v1.x; a1[4 * k + 1] += v1.y; a1[4 * k + 2] += v1.z; a1[4 * k + 3] += v1.w;
                a2[4 * k] += v2.x; a2[4 * k + 1] += v2.y; a2[4 * k + 2] += v2.z; a2[4 * k + 3] += v2.w;
            }
            nn += row[128] + row[129];
        }
        float rn = 1.f / nn;
        const float4* X4 = (const float4*)(X + (size_t)b * 64 + d0);
        float4* O4 = (float4*)(out + (size_t)b * 64 + d0);
        #pragma unroll
        for (int k = 0; k < 4; k++) {
            float4 xv = X4[k];
            float4 o;
            o.x = (xv.x * a1[4 * k]     + a2[4 * k])     * rn;
            o.y = (xv.y * a1[4 * k + 1] + a2[4 * k + 1]) * rn;
            o.z = (xv.z * a1[4 * k + 2] + a2[4 * k + 2]) * rn;
            o.w = (xv.w * a1[4 * k + 3] + a2[4 * k + 3]) * rn;
            O4[k] = o;
        }
    }
}

extern "C" void kernel_launch(void* const* d_in, const int* in_sizes, int n_in,
                              void* d_out, int out_size, void* d_ws, size_t ws_size,
                              hipStream_t stream) {
    (void)in_sizes; (void)n_in; (void)out_size; (void)ws_size;
    const float* X   = (const float*)d_in[0];
    const float* Mu0 = (const float*)d_in[1];
    const float* Mu1 = (const float*)d_in[2];
    const float* S0  = (const float*)d_in[3];
    const float* S1  = (const float*)d_in[4];
    const float* Lam = (const float*)d_in[5];
    const float* T   = (const float*)d_in[6];
    const float* E   = (const float*)d_in[7];

    char* ws = (char*)d_ws;
    int*   cnt  = (int*)ws;                 // 128 B (32 counters)
    float* part = (float*)(ws + 256);       // 17.3 MB

    hipMemsetAsync(cnt, 0, 128, stream);
    dim3 grid(B_N / BT, NSPLIT);
    gmm_main_kernel<<<grid, 256, 0, stream>>>(X, Mu0, Mu1, S0, S1, Lam, T, E,
                                              part, cnt, (float*)d_out);
}

// Round 7
// 96.540 us; speedup vs baseline: 1.2940x; 1.2940x over previous
//
#include <hip/hip_runtime.h>
#include <math.h>

// GMMflow_fast: B=2048, M=1024, D=64.  R7 = R6 fused prep+main, R5 finalize.
//   Inline prep (per block, its 64 m): a=1/Sigma, p'=-2*mut*a, q[m]; K,g stashed bf16.
//   GEMM1 (3-pass bf16 hi/lo, K=128): C1[b,m] = A1[b,:]·B1[m,:], A1=[x^2|x], B1=[a|p']
//   w = exp(clip(-0.5*(C1+q)))*Lam; norm via shfl-reduce of bf16-rounded w
//   GEMM2 (single bf16, K=64m, N=128): C3 = W·V, V=[K|g]
//   Partials [split][b][132] -> finalize kernel (512 blocks, full GPU) reduces.
// R6 lesson: last-block-reduces tail (32 blocks, 17 MB, post-fence) cost ~50 us;
// the separate finalize does it in ~3 us. Keep reduction at full-grid parallelism.

#define B_N 2048
#define M_N 1024
#define NSPLIT 16
#define BT 64
#define MS 64
#define PROW 132   // 64 S1 | 64 S2 | norm0 norm1 | pad

typedef short bf16x8 __attribute__((ext_vector_type(8)));
typedef float f32x4 __attribute__((ext_vector_type(4)));

static __device__ __forceinline__ unsigned short bf16rn(float f) {
    union { float f; unsigned u; } v; v.f = f;
    unsigned r = v.u + 0x7FFF + ((v.u >> 16) & 1);
    return (unsigned short)(r >> 16);
}
static __device__ __forceinline__ float bf2f(unsigned short h) {
    union { unsigned u; float f; } v; v.u = ((unsigned)h) << 16;
    return v.f;
}
static __device__ __forceinline__ void st4(unsigned short* p, unsigned short a,
                                           unsigned short b, unsigned short c, unsigned short d) {
    union { unsigned short u[4]; float2 f; } t;
    t.u[0] = a; t.u[1] = b; t.u[2] = c; t.u[3] = d;
    *(float2*)p = t.f;
}

// grid (32,16) = 512 blocks, 256 thr, ~70 KB LDS, 2 blocks/CU.
__global__ __launch_bounds__(256, 2)
void gmm_main_kernel(const float* __restrict__ X,
                     const float* __restrict__ Mu0, const float* __restrict__ Mu1,
                     const float* __restrict__ S0, const float* __restrict__ S1,
                     const float* __restrict__ Lam,
                     const float* __restrict__ T, const float* __restrict__ E,
                     float* __restrict__ part) {
    __shared__ __align__(16) char smem_raw[70144];
    unsigned short* sm = (unsigned short*)smem_raw;
    unsigned short* sA1h = sm;                // 8704 us
    unsigned short* sA1l = sm + 8704;
    unsigned short* sB1h = sm + 17408;
    unsigned short* sB1l = sm + 26112;        // region end 34816 us (69632 B)
    unsigned short* sV   = sm;                // overlay on A: 128x72 = 9216 us
    unsigned short* sW   = sm + 17408;        // overlay on B: 64x72 = 4608 us
    float* sQ = (float*)(smem_raw + 69632);   // 64 f
    float* sL = (float*)(smem_raw + 69888);   // 64 f

    const int tid  = threadIdx.x;
    const int Boff = blockIdx.x * BT;
    const int Moff = blockIdx.y * MS;
    const int w    = tid >> 6;
    const int lane = tid & 63;
    const int c = lane & 15, q = lane >> 4;
    const int wb = w >> 1;     // b-half
    const int wm = w & 1;      // GEMM1 m-half / GEMM2 n-half
    const int d  = lane;       // prep: dim index
    const int mq = tid >> 6;   // prep: m-subgroup

    // ---- inline prep: component math for this block's 64 m ----
    ushort2 kg[16];   // stashed bf16 (K,g) per handled (m,d)
    {
        const float t = T[0], e = E[0];
        const float eps2 = e * e, eps4 = eps2 * eps2, omt = 1.f - t;
        #pragma unroll 4
        for (int it = 0; it < 16; it++) {
            int mloc = it * 4 + mq;
            int idx = (Moff + mloc) * 64 + d;
            float s0 = S0[idx], s1 = S1[idx];
            float mu0 = Mu0[idx], mu1 = Mu1[idx];
            float Ds = sqrtf(4.f * s0 * s1 + eps4);
            float Cs = 0.5f * (Ds - eps2);
            float sig = omt * omt * s0 + t * t * s1 + 2.f * t * omt * (Cs + 0.5f * eps2);
            float St = (t * s1 + omt * Cs) - (omt * s0 + t * Cs) - eps2 * t;
            float a = 1.f / sig;
            float K = St * a;
            float mut = omt * mu0 + t * mu1;
            float pp = -2.f * mut * a;
            float g = (mu1 - mu0) - K * mut;
            unsigned short ah = bf16rn(a);
            sB1h[mloc * 136 + d] = ah;
            sB1l[mloc * 136 + d] = bf16rn(a - bf2f(ah));
            unsigned short ph = bf16rn(pp);
            sB1h[mloc * 136 + 64 + d] = ph;
            sB1l[mloc * 136 + 64 + d] = bf16rn(pp - bf2f(ph));
            kg[it] = make_ushort2(bf16rn(K), bf16rn(g));
            float qd = mut * mut * a + __logf(sig);
            #pragma unroll
            for (int off = 32; off > 0; off >>= 1) qd += __shfl_xor(qd, off, 64);
            if (d == 0) sQ[mloc] = qd;
        }
        if (tid < 64) sL[tid] = Lam[Moff + tid];
    }
    // ---- stage A1 from X (hi/lo of x^2, x) ----
    {
        const float4* X4 = (const float4*)X;
        #pragma unroll
        for (int it = 0; it < 4; it++) {
            int i = it * 256 + tid;            // 64 b x 16 f4
            int b = i >> 4, dq4 = i & 15;
            float4 xv = X4[(size_t)(Boff + b) * 16 + dq4];
            float xs[4] = {xv.x, xv.y, xv.z, xv.w};
            unsigned short yh[4], yl[4], xh[4], xl[4];
            #pragma unroll
            for (int k = 0; k < 4; k++) {
                float y = xs[k] * xs[k];
                yh[k] = bf16rn(y);  yl[k] = bf16rn(y - bf2f(yh[k]));
                xh[k] = bf16rn(xs[k]);  xl[k] = bf16rn(xs[k] - bf2f(xh[k]));
            }
            int base = b * 136 + 4 * dq4;
            st4(sA1h + base, yh[0], yh[1], yh[2], yh[3]);
            st4(sA1l + base, yl[0], yl[1], yl[2], yl[3]);
            st4(sA1h + base + 64, xh[0], xh[1], xh[2], xh[3]);
            st4(sA1l + base + 64, xl[0], xl[1], xl[2], xl[3]);
        }
    }
    __syncthreads();

    // ---- GEMM1: wave quadrant 32b x 32m, K=128, 3 hi/lo passes ----
    f32x4 acc1[2][2];
    #pragma unroll
    for (int i = 0; i < 2; i++)
        #pragma unroll
        for (int j = 0; j < 2; j++) acc1[i][j] = (f32x4){0.f, 0.f, 0.f, 0.f};
    #pragma unroll
    for (int ks = 0; ks < 4; ks++) {
        bf16x8 Ah[2], Al[2], Bh[2], Bl[2];
        #pragma unroll
        for (int i = 0; i < 2; i++) {
            int row = wb * 32 + i * 16 + c;
            Ah[i] = *(const bf16x8*)(sA1h + row * 136 + ks * 32 + q * 8);
            Al[i] = *(const bf16x8*)(sA1l + row * 136 + ks * 32 + q * 8);
        }
        #pragma unroll
        for (int j = 0; j < 2; j++) {
            int row = wm * 32 + j * 16 + c;
            Bh[j] = *(const bf16x8*)(sB1h + row * 136 + ks * 32 + q * 8);
            Bl[j] = *(const bf16x8*)(sB1l + row * 136 + ks * 32 + q * 8);
        }
        #pragma unroll
        for (int i = 0; i < 2; i++)
            #pragma unroll
            for (int j = 0; j < 2; j++) {
                acc1[i][j] = __builtin_amdgcn_mfma_f32_16x16x32_bf16(Ah[i], Bh[j], acc1[i][j], 0, 0, 0);
                acc1[i][j] = __builtin_amdgcn_mfma_f32_16x16x32_bf16(Ah[i], Bl[j], acc1[i][j], 0, 0, 0);
                acc1[i][j] = __builtin_amdgcn_mfma_f32_16x16x32_bf16(Al[i], Bh[j], acc1[i][j], 0, 0, 0);
            }
    }
    __syncthreads();   // A/B regions dead -> overlays

    // ---- write V from stashed kg + compute W + consistent norm ----
    {
        #pragma unroll 4
        for (int it = 0; it < 16; it++) {
            int mloc = it * 4 + mq;
            sV[d * 72 + mloc]        = kg[it].x;   // K rows n=0..63
            sV[(64 + d) * 72 + mloc] = kg[it].y;   // g rows n=64..127
        }
        float nsum[2][4];
        #pragma unroll
        for (int i = 0; i < 2; i++)
            #pragma unroll
            for (int r = 0; r < 4; r++) nsum[i][r] = 0.f;
        #pragma unroll
        for (int i = 0; i < 2; i++)
            #pragma unroll
            for (int j = 0; j < 2; j++) {
                int m = wm * 32 + j * 16 + c;
                float qm = sQ[m], lm = sL[m];
                #pragma unroll
                for (int r = 0; r < 4; r++) {
                    int bl = wb * 32 + i * 16 + q * 4 + r;
                    float lw = -0.5f * (acc1[i][j][r] + qm);
                    lw = fminf(50.f, fmaxf(-50.f, lw));
                    float wf = __expf(lw) * lm;
                    unsigned short wh = bf16rn(wf);
                    sW[bl * 72 + m] = wh;
                    nsum[i][r] += bf2f(wh);
                }
            }
        #pragma unroll
        for (int mask = 1; mask <= 8; mask <<= 1)
            #pragma unroll
            for (int i = 0; i < 2; i++)
                #pragma unroll
                for (int r = 0; r < 4; r++)
                    nsum[i][r] += __shfl_xor(nsum[i][r], mask, 64);
        if (c == 0) {
            #pragma unroll
            for (int i = 0; i < 2; i++)
                #pragma unroll
                for (int r = 0; r < 4; r++) {
                    int b = Boff + wb * 32 + i * 16 + q * 4 + r;
                    part[((size_t)blockIdx.y * B_N + b) * PROW + 128 + wm] = nsum[i][r];
                }
        }
    }
    __syncthreads();

    // ---- GEMM2: wave 32b x 64n, K=64, single pass ----
    f32x4 acc2[2][4];
    #pragma unroll
    for (int i = 0; i < 2; i++)
        #pragma unroll
        for (int j = 0; j < 4; j++) acc2[i][j] = (f32x4){0.f, 0.f, 0.f, 0.f};
    #pragma unroll
    for (int ks = 0; ks < 2; ks++) {
        bf16x8 Wf[2], Vf[4];
        #pragma unroll
        for (int i = 0; i < 2; i++) {
            int row = wb * 32 + i * 16 + c;
            Wf[i] = *(const bf16x8*)(sW + row * 72 + ks * 32 + q * 8);
        }
        #pragma unroll
        for (int j = 0; j < 4; j++) {
            int row = wm * 64 + j * 16 + c;
            Vf[j] = *(const bf16x8*)(sV + row * 72 + ks * 32 + q * 8);
        }
        #pragma unroll
        for (int i = 0; i < 2; i++)
            #pragma unroll
            for (int j = 0; j < 4; j++)
                acc2[i][j] = __builtin_amdgcn_mfma_f32_16x16x32_bf16(Wf[i], Vf[j], acc2[i][j], 0, 0, 0);
    }

    // ---- partial S1|S2 writes ----
    #pragma unroll
    for (int i = 0; i < 2; i++)
        #pragma unroll
        for (int j = 0; j < 4; j++) {
            #pragma unroll
            for (int r = 0; r < 4; r++) {
                int b = Boff + wb * 32 + i * 16 + q * 4 + r;
                int n = wm * 64 + j * 16 + c;
                part[((size_t)blockIdx.y * B_N + b) * PROW + n] = acc2[i][j][r];
            }
        }
}

// ---------------- finalize: reduce splits at full-grid parallelism ----------------
__global__ __launch_bounds__(256)
void finalize_kernel(const float* __restrict__ X, const float* __restrict__ part,
                     float* __restrict__ out) {
    int gid = blockIdx.x * 256 + threadIdx.x;   // 131072
    int b = gid >> 6, d = gid & 63;
    float a1 = 0.f, a2 = 0.f, nn = 0.f;
    #pragma unroll
    for (int s = 0; s < NSPLIT; s++) {
        const float* row = part + ((size_t)s * B_N + b) * PROW;
        a1 += row[d];
        a2 += row[64 + d];
        nn += row[128] + row[129];
    }
    out[gid] = (X[gid] * a1 + a2) / nn;
}

extern "C" void kernel_launch(void* const* d_in, const int* in_sizes, int n_in,
                              void* d_out, int out_size, void* d_ws, size_t ws_size,
                              hipStream_t stream) {
    (void)in_sizes; (void)n_in; (void)out_size; (void)ws_size;
    const float* X   = (const float*)d_in[0];
    const float* Mu0 = (const float*)d_in[1];
    const float* Mu1 = (const float*)d_in[2];
    const float* S0  = (const float*)d_in[3];
    const float* S1  = (const float*)d_in[4];
    const float* Lam = (const float*)d_in[5];
    const float* T   = (const float*)d_in[6];
    const float* E   = (const float*)d_in[7];

    float* part = (float*)d_ws;   // 17.3 MB

    dim3 grid(B_N / BT, NSPLIT);
    gmm_main_kernel<<<grid, 256, 0, stream>>>(X, Mu0, Mu1, S0, S1, Lam, T, E, part);
    finalize_kernel<<<512, 256, 0, stream>>>(X, part, (float*)d_out);
}

// Round 8
// 83.673 us; speedup vs baseline: 1.4930x; 1.1538x over previous
//
#include <hip/hip_runtime.h>
#include <math.h>

// GMMflow_fast: B=2048, M=1024, D=64.  R8 = R5 structure + micro-opts.
//   prep (256 blocks): a=1/Sigma, p'=-2*mut*a (bf16 hi/lo), VT=[K|g] bf16, q[m] f32.
//   main (grid 32x16, 2 blk/CU): GEMM1 3-pass bf16 hi/lo K=128 (A1=[x^2|x] built
//     in-kernel, B1=[a|p']); w=exp(clip(-0.5*(C1+q)))*Lam; norm via shfl of
//     bf16-rounded w (consistent with GEMM2's W); GEMM2 single bf16 K=64m.
//     Partials: S1|S2 as bf16 (halves traffic; norms f32 — common-mode per b).
//   finalize (256 blocks x 128): reduce 16 splits, u=(x*S1+S2)/n.
// R6 lesson: reductions need full-grid parallelism. R7 lesson: no redundant
// per-block prep — amortize in a small dispatch.

#define B_N 2048
#define M_N 1024
#define NSPLIT 16
#define BT 64
#define MS 64

typedef short bf16x8 __attribute__((ext_vector_type(8)));
typedef float f32x4 __attribute__((ext_vector_type(4)));

static __device__ __forceinline__ unsigned short bf16rn(float f) {
    union { float f; unsigned u; } v; v.f = f;
    unsigned r = v.u + 0x7FFF + ((v.u >> 16) & 1);
    return (unsigned short)(r >> 16);
}
static __device__ __forceinline__ float bf2f(unsigned short h) {
    union { unsigned u; float f; } v; v.u = ((unsigned)h) << 16;
    return v.f;
}
static __device__ __forceinline__ void st4(unsigned short* p, unsigned short a,
                                           unsigned short b, unsigned short c, unsigned short d) {
    union { unsigned short u[4]; float2 f; } t;
    t.u[0] = a; t.u[1] = b; t.u[2] = c; t.u[3] = d;
    *(float2*)p = t.f;
}

// ---------------- prep: 256 blocks x 4 m, 1 (m,d) pair per thread ----------------
__global__ __launch_bounds__(256)
void prep_kernel(const float* __restrict__ Mu0, const float* __restrict__ Mu1,
                 const float* __restrict__ S0, const float* __restrict__ S1,
                 const float* __restrict__ T, const float* __restrict__ E,
                 unsigned short* __restrict__ B1h, unsigned short* __restrict__ B1l,
                 unsigned short* __restrict__ VTh, float* __restrict__ qArr) {
    __shared__ float sK[4 * 65];
    __shared__ float sG[4 * 65];
    const int tid = threadIdx.x;
    const int m0 = blockIdx.x * 4;
    const int mi = tid >> 6, d = tid & 63;
    const int m = m0 + mi;
    const float t = T[0], e = E[0];
    const float eps2 = e * e, eps4 = eps2 * eps2, omt = 1.f - t;
    int idx = m * 64 + d;
    float s0 = S0[idx], s1 = S1[idx];
    float mu0 = Mu0[idx], mu1 = Mu1[idx];
    float Ds = sqrtf(4.f * s0 * s1 + eps4);
    float Cs = 0.5f * (Ds - eps2);
    float sig = omt * omt * s0 + t * t * s1 + 2.f * t * omt * (Cs + 0.5f * eps2);
    float St = (t * s1 + omt * Cs) - (omt * s0 + t * Cs) - eps2 * t;
    float a = 1.f / sig;
    float K = St * a;
    float mut = omt * mu0 + t * mu1;
    float pp = -2.f * mut * a;
    float g = (mu1 - mu0) - K * mut;
    unsigned short ah = bf16rn(a);
    B1h[m * 128 + d] = ah;
    B1l[m * 128 + d] = bf16rn(a - bf2f(ah));
    unsigned short ph = bf16rn(pp);
    B1h[m * 128 + 64 + d] = ph;
    B1l[m * 128 + 64 + d] = bf16rn(pp - bf2f(ph));
    sK[mi * 65 + d] = K;
    sG[mi * 65 + d] = g;
    float qd = mut * mut * a + __logf(sig);
    #pragma unroll
    for (int off = 32; off > 0; off >>= 1) qd += __shfl_xor(qd, off, 64);
    if (d == 0) qArr[m] = qd;
    __syncthreads();
    // VT[n][m] transpose write: 128 n x 4 m
    #pragma unroll
    for (int it = 0; it < 2; it++) {
        int i = it * 256 + tid;
        int n = i >> 2, mm = i & 3;
        float v = (n < 64) ? sK[mm * 65 + n] : sG[mm * 65 + (n - 64)];
        VTh[n * M_N + m0 + mm] = bf16rn(v);
    }
}

// ---------------- main: grid (32,16), 256 thr, ~70 KB LDS, 2 blocks/CU ----------------
__global__ __launch_bounds__(256, 2)
void gmm_main_kernel(const float* __restrict__ X, const float* __restrict__ Lam,
                     const unsigned short* __restrict__ B1h, const unsigned short* __restrict__ B1l,
                     const unsigned short* __restrict__ VTh,
                     const float* __restrict__ qArr,
                     unsigned short* __restrict__ partBF, float* __restrict__ partN) {
    __shared__ __align__(16) char smem_raw[70144];
    unsigned short* sm = (unsigned short*)smem_raw;
    unsigned short* sA1h = sm;                // 8704 us
    unsigned short* sA1l = sm + 8704;
    unsigned short* sB1h = sm + 17408;
    unsigned short* sB1l = sm + 26112;        // region end 34816 us
    unsigned short* sV   = sm;                // overlay on A: 128x72 = 9216 us
    unsigned short* sW   = sm + 17408;        // overlay on B: 64x72 = 4608 us
    float* sQ = (float*)(smem_raw + 69632);
    float* sL = (float*)(smem_raw + 69888);

    const int tid  = threadIdx.x;
    const int Boff = blockIdx.x * BT;
    const int Moff = blockIdx.y * MS;
    const int w    = tid >> 6;
    const int lane = tid & 63;
    const int c = lane & 15, q = lane >> 4;
    const int wb = w >> 1;     // b-half
    const int wm = w & 1;      // GEMM1 m-half / GEMM2 n-half

    // ---- stage A1 from X (hi/lo of x^2, x); copy B1 h/l from global ----
    {
        const float4* X4 = (const float4*)X;
        #pragma unroll
        for (int it = 0; it < 4; it++) {
            int i = it * 256 + tid;            // 64 b x 16 f4
            int b = i >> 4, dq4 = i & 15;
            float4 xv = X4[(size_t)(Boff + b) * 16 + dq4];
            float xs[4] = {xv.x, xv.y, xv.z, xv.w};
            unsigned short yh[4], yl[4], xh[4], xl[4];
            #pragma unroll
            for (int k = 0; k < 4; k++) {
                float y = xs[k] * xs[k];
                yh[k] = bf16rn(y);  yl[k] = bf16rn(y - bf2f(yh[k]));
                xh[k] = bf16rn(xs[k]);  xl[k] = bf16rn(xs[k] - bf2f(xh[k]));
            }
            int base = b * 136 + 4 * dq4;
            st4(sA1h + base, yh[0], yh[1], yh[2], yh[3]);
            st4(sA1l + base, yl[0], yl[1], yl[2], yl[3]);
            st4(sA1h + base + 64, xh[0], xh[1], xh[2], xh[3]);
            st4(sA1l + base + 64, xl[0], xl[1], xl[2], xl[3]);
        }
        const float4* gBh = (const float4*)B1h + (size_t)Moff * 16;
        const float4* gBl = (const float4*)B1l + (size_t)Moff * 16;
        #pragma unroll
        for (int it = 0; it < 4; it++) {
            int i = it * 256 + tid;            // 64 m x 16 f4
            int row = i >> 4, cc = i & 15;
            *(float4*)(sB1h + row * 136 + cc * 8) = gBh[row * 16 + cc];
            *(float4*)(sB1l + row * 136 + cc * 8) = gBl[row * 16 + cc];
        }
        if (tid < 64) sQ[tid] = qArr[Moff + tid];
        else if (tid < 128) sL[tid - 64] = Lam[Moff + tid - 64];
    }
    __syncthreads();

    // ---- GEMM1: wave quadrant 32b x 32m, K=128, 3 hi/lo passes ----
    f32x4 acc1[2][2];
    #pragma unroll
    for (int i = 0; i < 2; i++)
        #pragma unroll
        for (int j = 0; j < 2; j++) acc1[i][j] = (f32x4){0.f, 0.f, 0.f, 0.f};
    #pragma unroll
    for (int ks = 0; ks < 4; ks++) {
        bf16x8 Ah[2], Al[2], Bh[2], Bl[2];
        #pragma unroll
        for (int i = 0; i < 2; i++) {
            int row = wb * 32 + i * 16 + c;
            Ah[i] = *(const bf16x8*)(sA1h + row * 136 + ks * 32 + q * 8);
            Al[i] = *(const bf16x8*)(sA1l + row * 136 + ks * 32 + q * 8);
        }
        #pragma unroll
        for (int j = 0; j < 2; j++) {
            int row = wm * 32 + j * 16 + c;
            Bh[j] = *(const bf16x8*)(sB1h + row * 136 + ks * 32 + q * 8);
            Bl[j] = *(const bf16x8*)(sB1l + row * 136 + ks * 32 + q * 8);
        }
        #pragma unroll
        for (int i = 0; i < 2; i++)
            #pragma unroll
            for (int j = 0; j < 2; j++) {
                acc1[i][j] = __builtin_amdgcn_mfma_f32_16x16x32_bf16(Ah[i], Bh[j], acc1[i][j], 0, 0, 0);
                acc1[i][j] = __builtin_amdgcn_mfma_f32_16x16x32_bf16(Ah[i], Bl[j], acc1[i][j], 0, 0, 0);
                acc1[i][j] = __builtin_amdgcn_mfma_f32_16x16x32_bf16(Al[i], Bh[j], acc1[i][j], 0, 0, 0);
            }
    }
    __syncthreads();   // A/B regions dead -> overlays

    // ---- stage V (bf16) + compute W + consistent norm ----
    {
        const float4* gV = (const float4*)VTh;   // row stride 128 f4
        int mo8 = Moff >> 3;
        #pragma unroll
        for (int it = 0; it < 4; it++) {
            int i = it * 256 + tid;              // 128 n x 8 f4
            int row = i >> 3, cc = i & 7;
            *(float4*)(sV + row * 72 + cc * 8) = gV[(size_t)row * 128 + mo8 + cc];
        }
        float nsum[2][4];
        #pragma unroll
        for (int i = 0; i < 2; i++)
            #pragma unroll
            for (int r = 0; r < 4; r++) nsum[i][r] = 0.f;
        #pragma unroll
        for (int i = 0; i < 2; i++)
            #pragma unroll
            for (int j = 0; j < 2; j++) {
                int m = wm * 32 + j * 16 + c;
                float qm = sQ[m], lm = sL[m];
                #pragma unroll
                for (int r = 0; r < 4; r++) {
                    int bl = wb * 32 + i * 16 + q * 4 + r;
                    float lw = -0.5f * (acc1[i][j][r] + qm);
                    lw = fminf(50.f, fmaxf(-50.f, lw));
                    float wf = __expf(lw) * lm;
                    unsigned short wh = bf16rn(wf);
                    sW[bl * 72 + m] = wh;
                    nsum[i][r] += bf2f(wh);
                }
            }
        #pragma unroll
        for (int mask = 1; mask <= 8; mask <<= 1)
            #pragma unroll
            for (int i = 0; i < 2; i++)
                #pragma unroll
                for (int r = 0; r < 4; r++)
                    nsum[i][r] += __shfl_xor(nsum[i][r], mask, 64);
        if (c == 0) {
            #pragma unroll
            for (int i = 0; i < 2; i++)
                #pragma unroll
                for (int r = 0; r < 4; r++) {
                    int b = Boff + wb * 32 + i * 16 + q * 4 + r;
                    partN[((size_t)blockIdx.y * B_N + b) * 2 + wm] = nsum[i][r];
                }
        }
    }
    __syncthreads();

    // ---- GEMM2: wave 32b x 64n, K=64, single pass ----
    f32x4 acc2[2][4];
    #pragma unroll
    for (int i = 0; i < 2; i++)
        #pragma unroll
        for (int j = 0; j < 4; j++) acc2[i][j] = (f32x4){0.f, 0.f, 0.f, 0.f};
    #pragma unroll
    for (int ks = 0; ks < 2; ks++) {
        bf16x8 Wf[2], Vf[4];
        #pragma unroll
        for (int i = 0; i < 2; i++) {
            int row = wb * 32 + i * 16 + c;
            Wf[i] = *(const bf16x8*)(sW + row * 72 + ks * 32 + q * 8);
        }
        #pragma unroll
        for (int j = 0; j < 4; j++) {
            int row = wm * 64 + j * 16 + c;
            Vf[j] = *(const bf16x8*)(sV + row * 72 + ks * 32 + q * 8);
        }
        #pragma unroll
        for (int i = 0; i < 2; i++)
            #pragma unroll
            for (int j = 0; j < 4; j++)
                acc2[i][j] = __builtin_amdgcn_mfma_f32_16x16x32_bf16(Wf[i], Vf[j], acc2[i][j], 0, 0, 0);
    }

    // ---- partial S1|S2 writes (bf16) ----
    #pragma unroll
    for (int i = 0; i < 2; i++)
        #pragma unroll
        for (int j = 0; j < 4; j++) {
            #pragma unroll
            for (int r = 0; r < 4; r++) {
                int b = Boff + wb * 32 + i * 16 + q * 4 + r;
                int n = wm * 64 + j * 16 + c;
                partBF[((size_t)blockIdx.y * B_N + b) * 128 + n] = bf16rn(acc2[i][j][r]);
            }
        }
}

// ---------------- finalize: 256 blocks x 128, thread per (b, d-quad) ----------------
__global__ __launch_bounds__(128)
void finalize_kernel(const float* __restrict__ X, const unsigned short* __restrict__ partBF,
                     const float* __restrict__ partN, float* __restrict__ out) {
    int gid = blockIdx.x * 128 + threadIdx.x;   // 32768 = 2048 b x 16 quads
    int b = gid >> 4, d0 = (gid & 15) * 4;
    float a1[4] = {0.f, 0.f, 0.f, 0.f}, a2[4] = {0.f, 0.f, 0.f, 0.f}, nn = 0.f;
    #pragma unroll
    for (int s = 0; s < NSPLIT; s++) {
        const unsigned short* row = partBF + ((size_t)s * B_N + b) * 128;
        ushort4 v1 = *(const ushort4*)(row + d0);
        ushort4 v2 = *(const ushort4*)(row + 64 + d0);
        a1[0] += bf2f(v1.x); a1[1] += bf2f(v1.y); a1[2] += bf2f(v1.z); a1[3] += bf2f(v1.w);
        a2[0] += bf2f(v2.x); a2[1] += bf2f(v2.y); a2[2] += bf2f(v2.z); a2[3] += bf2f(v2.w);
        float2 nv = *(const float2*)(partN + ((size_t)s * B_N + b) * 2);
        nn += nv.x + nv.y;
    }
    float rn = 1.f / nn;
    float4 xv = *(const float4*)(X + (size_t)b * 64 + d0);
    float4 o;
    o.x = (xv.x * a1[0] + a2[0]) * rn;
    o.y = (xv.y * a1[1] + a2[1]) * rn;
    o.z = (xv.z * a1[2] + a2[2]) * rn;
    o.w = (xv.w * a1[3] + a2[3]) * rn;
    *(float4*)(out + (size_t)b * 64 + d0) = o;
}

extern "C" void kernel_launch(void* const* d_in, const int* in_sizes, int n_in,
                              void* d_out, int out_size, void* d_ws, size_t ws_size,
                              hipStream_t stream) {
    (void)in_sizes; (void)n_in; (void)out_size; (void)ws_size;
    const float* X   = (const float*)d_in[0];
    const float* Mu0 = (const float*)d_in[1];
    const float* Mu1 = (const float*)d_in[2];
    const float* S0  = (const float*)d_in[3];
    const float* S1  = (const float*)d_in[4];
    const float* Lam = (const float*)d_in[5];
    const float* T   = (const float*)d_in[6];
    const float* E   = (const float*)d_in[7];

    char* ws = (char*)d_ws;
    unsigned short* B1h   = (unsigned short*)(ws);              // 256 KB
    unsigned short* B1l   = (unsigned short*)(ws + 262144);     // 256 KB
    unsigned short* VTh   = (unsigned short*)(ws + 524288);     // 256 KB
    float*          qArr  = (float*)(ws + 786432);              // 4 KB
    unsigned short* partBF= (unsigned short*)(ws + 790528);     // 8.39 MB
    float*          partN = (float*)(ws + 790528 + 8388608);    // 512 KB

    prep_kernel<<<256, 256, 0, stream>>>(Mu0, Mu1, S0, S1, T, E, B1h, B1l, VTh, qArr);
    dim3 grid(B_N / BT, NSPLIT);
    gmm_main_kernel<<<grid, 256, 0, stream>>>(X, Lam, B1h, B1l, VTh, qArr, partBF, partN);
    finalize_kernel<<<256, 128, 0, stream>>>(X, partBF, partN, (float*)d_out);
}